// Round 1
// baseline (312.173 us; speedup 1.0000x reference)
//
#include <hip/hip_runtime.h>
#include <hip/hip_bf16.h>

#define NT 4096      // tokens
#define DIM 768
#define NE 1536      // experts
#define ED 64        // expert dim

// ---------------- Kernel 1: gating GEMM (fp32) ----------------
// scores[n][e] = dot(x[n,:], gate_w[e,:]) + gate_b[e] + 0.1*noise[n][e]
// BM=128, BN=64, BK=32, 256 threads, per-thread 8x4 microtile.
// LDS column swizzle: col = (k + 4*(row>>3)) & 31  (16B-aligned, conflict-free frag reads)
__global__ __launch_bounds__(256) void gate_gemm(
    const float* __restrict__ x, const float* __restrict__ gw,
    const float* __restrict__ gb, const float* __restrict__ noise,
    float* __restrict__ scores) {
  constexpr int BM = 128, BN = 64, BK = 32, TM = 8, TN = 4;
  __shared__ float As[BM][BK];
  __shared__ float Bs[BN][BK];
  const int bm = blockIdx.x;           // 0..31
  const int bn = blockIdx.y;           // 0..23
  const int tid = threadIdx.x;
  const int tr = tid >> 4;             // 0..15
  const int tc = tid & 15;             // 0..15
  const int m0 = tr * TM;              // 0..120
  const int n0 = tc * TN;              // 0..60

  float acc[TM][TN] = {};

  const float* Ab = x + (size_t)(bm * BM) * DIM;
  const float* Bb = gw + (size_t)(bn * BN) * DIM;

  for (int kt = 0; kt < DIM; kt += BK) {
    // load A tile: 128x32 = 1024 float4, 4 per thread
#pragma unroll
    for (int i = 0; i < 4; i++) {
      int f = tid + 256 * i;
      int r = f >> 3;
      int k0 = (f & 7) * 4;
      float4 v = *(const float4*)(Ab + r * DIM + kt + k0);
      int col = (k0 + 4 * (r >> 3)) & 31;
      *(float4*)&As[r][col] = v;
    }
    // load B tile: 64x32 = 512 float4, 2 per thread
#pragma unroll
    for (int i = 0; i < 2; i++) {
      int f = tid + 256 * i;
      int r = f >> 3;
      int k0 = (f & 7) * 4;
      float4 v = *(const float4*)(Bb + r * DIM + kt + k0);
      int col = (k0 + 4 * (r >> 3)) & 31;
      *(float4*)&Bs[r][col] = v;
    }
    __syncthreads();

#pragma unroll
    for (int kk = 0; kk < BK; kk += 4) {
      float4 a4[TM];
      float4 b4[TN];
      const int ca = (kk + 4 * tr) & 31;         // (m0+i)>>3 == tr for all i
      const int cb = (kk + 4 * (tc >> 1)) & 31;  // (n0+j)>>3 == tc>>1 for all j
#pragma unroll
      for (int i = 0; i < TM; i++) a4[i] = *(const float4*)&As[m0 + i][ca];
#pragma unroll
      for (int j = 0; j < TN; j++) b4[j] = *(const float4*)&Bs[n0 + j][cb];
#pragma unroll
      for (int i = 0; i < TM; i++)
#pragma unroll
        for (int j = 0; j < TN; j++) {
          acc[i][j] += a4[i].x * b4[j].x;
          acc[i][j] += a4[i].y * b4[j].y;
          acc[i][j] += a4[i].z * b4[j].z;
          acc[i][j] += a4[i].w * b4[j].w;
        }
    }
    __syncthreads();
  }

  // epilogue: + gate_b + 0.1*noise, write scores
  const int gm0 = bm * BM + m0;
  const int gn0 = bn * BN + n0;
  float4 gbv = *(const float4*)(gb + gn0);
#pragma unroll
  for (int i = 0; i < TM; i++) {
    int gm = gm0 + i;
    float4 nz = *(const float4*)(noise + (size_t)gm * NE + gn0);
    float4 o;
    o.x = acc[i][0] + gbv.x + 0.1f * nz.x;
    o.y = acc[i][1] + gbv.y + 0.1f * nz.y;
    o.z = acc[i][2] + gbv.z + 0.1f * nz.z;
    o.w = acc[i][3] + gbv.w + 0.1f * nz.w;
    *(float4*)(scores + (size_t)gm * NE + gn0) = o;
  }
}

// ---------------- Kernel 2: softmax top-1 (one wave per token) ----------------
__global__ __launch_bounds__(256) void softmax_top1(
    const float* __restrict__ scores, float* __restrict__ topw,
    int* __restrict__ idx, int* __restrict__ counts) {
  const int widx = threadIdx.x >> 6;
  const int lane = threadIdx.x & 63;
  const int n = blockIdx.x * 4 + widx;
  const float* s = scores + (size_t)n * NE;

  float v[24];
  float m = -1e30f;
  int mi = 0;
#pragma unroll
  for (int j = 0; j < 24; j++) {
    v[j] = s[lane + 64 * j];
    int ii = lane + 64 * j;
    if (v[j] > m) { m = v[j]; mi = ii; }   // strict > keeps lowest index within lane
  }
  // wave reduce max with lowest-index tiebreak
#pragma unroll
  for (int off = 32; off; off >>= 1) {
    float om = __shfl_xor(m, off, 64);
    int oi = __shfl_xor(mi, off, 64);
    if (om > m || (om == m && oi < mi)) { m = om; mi = oi; }
  }
  float sum = 0.f;
#pragma unroll
  for (int j = 0; j < 24; j++) sum += __expf(v[j] - m);
#pragma unroll
  for (int off = 32; off; off >>= 1) sum += __shfl_xor(sum, off, 64);

  if (lane == 0) {
    topw[n] = 1.0f / sum;   // exp(max-max)/sum
    idx[n] = mi;
    atomicAdd(counts + mi, 1);
  }
}

// ---------------- Kernel 3: exclusive scan of counts (1536 = 256*6) ----------------
__global__ __launch_bounds__(256) void scan_offsets(
    const int* __restrict__ counts, int* __restrict__ offs, int* __restrict__ cursor) {
  __shared__ int part[256];
  const int t = threadIdx.x;
  int loc[6];
  int s = 0;
#pragma unroll
  for (int j = 0; j < 6; j++) { loc[j] = counts[t * 6 + j]; s += loc[j]; }
  part[t] = s;
  __syncthreads();
  for (int d = 1; d < 256; d <<= 1) {
    int v2 = (t >= d) ? part[t - d] : 0;
    __syncthreads();
    part[t] += v2;
    __syncthreads();
  }
  int excl = part[t] - s;
#pragma unroll
  for (int j = 0; j < 6; j++) {
    offs[t * 6 + j] = excl;
    cursor[t * 6 + j] = excl;
    excl += loc[j];
  }
}

// ---------------- Kernel 4: scatter token ids grouped by expert ----------------
__global__ __launch_bounds__(256) void scatter_tokens(
    const int* __restrict__ idx, int* __restrict__ cursor, int* __restrict__ sorted) {
  const int n = blockIdx.x * 256 + threadIdx.x;
  int e = idx[n];
  int pos = atomicAdd(cursor + e, 1);
  sorted[pos] = n;
}

// ---------------- Kernel 5: per-expert GEMV batch ----------------
// One block per expert; reads the expert's 64x768 weights exactly once (if used).
__global__ __launch_bounds__(256) void expert_gemm(
    const float* __restrict__ x, const float* __restrict__ ew,
    const float* __restrict__ eb, const int* __restrict__ counts,
    const int* __restrict__ offs, const int* __restrict__ sorted,
    float* __restrict__ y) {
  const int e = blockIdx.x;
  const int cnt = counts[e];
  if (cnt == 0) return;
  const int base = offs[e];
  __shared__ float4 xs4[8 * 192];  // up to 8 tokens of x
  __shared__ int tok[8];
  const int tid = threadIdx.x;
  const int w = tid >> 6;
  const int lane = tid & 63;
  const float4* W4 = (const float4*)(ew + (size_t)e * ED * DIM);
  const float4* X4 = (const float4*)x;

  for (int c0 = 0; c0 < cnt; c0 += 8) {
    int cc = min(8, cnt - c0);
    __syncthreads();  // protect tok/xs4 from previous iteration's readers
    if (tid < cc) tok[tid] = sorted[base + c0 + tid];
    __syncthreads();
    int nf = cc * 192;
    for (int f = tid; f < nf; f += 256) {
      int t = f / 192, p = f % 192;
      xs4[t * 192 + p] = X4[(size_t)tok[t] * 192 + p];
    }
    __syncthreads();

    for (int oi = 0; oi < 16; oi++) {
      int o = w * 16 + oi;
      float4 w4a = W4[(size_t)o * 192 + lane];
      float4 w4b = W4[(size_t)o * 192 + lane + 64];
      float4 w4c = W4[(size_t)o * 192 + lane + 128];
      for (int t = 0; t < cc; t++) {
        float4 xa = xs4[t * 192 + lane];
        float4 xb = xs4[t * 192 + lane + 64];
        float4 xc = xs4[t * 192 + lane + 128];
        float p = w4a.x * xa.x + w4a.y * xa.y + w4a.z * xa.z + w4a.w * xa.w;
        p += w4b.x * xb.x + w4b.y * xb.y + w4b.z * xb.z + w4b.w * xb.w;
        p += w4c.x * xc.x + w4c.y * xc.y + w4c.z * xc.z + w4c.w * xc.w;
#pragma unroll
        for (int off = 32; off; off >>= 1) p += __shfl_xor(p, off, 64);
        if (lane == 0) y[(size_t)tok[t] * ED + o] = p + eb[e * ED + o];
      }
    }
  }
}

// ---------------- Kernel 6: projection + scale by top_w ----------------
__global__ __launch_bounds__(256) void proj_kernel(
    const float* __restrict__ y, const float* __restrict__ pw,
    const float* __restrict__ pb, const float* __restrict__ topw,
    float* __restrict__ out) {
  const int b = blockIdx.x;  // 512 blocks x 8 tokens
  const int tid = threadIdx.x;
  __shared__ float4 ys4[8 * 16];
  __shared__ float tw[8];
  if (tid < 128) {
    int t = tid >> 4, q = tid & 15;
    ys4[tid] = ((const float4*)y)[((size_t)b * 8 + t) * 16 + q];
  }
  if (tid < 8) tw[tid] = topw[b * 8 + tid];
  __syncthreads();
  const float4* pw4 = (const float4*)pw;
  for (int c = 0; c < 3; c++) {
    int d = c * 256 + tid;
    float4 pwv[16];
#pragma unroll
    for (int q = 0; q < 16; q++) pwv[q] = pw4[(size_t)d * 16 + q];
    float pbv = pb[d];
    for (int t = 0; t < 8; t++) {
      float s = 0.f;
#pragma unroll
      for (int q = 0; q < 16; q++) {
        float4 yv = ys4[t * 16 + q];
        s += pwv[q].x * yv.x + pwv[q].y * yv.y + pwv[q].z * yv.z + pwv[q].w * yv.w;
      }
      out[((size_t)b * 8 + t) * DIM + d] = (s + pbv) * tw[t];
    }
  }
}

// ---------------- launch ----------------
extern "C" void kernel_launch(void* const* d_in, const int* in_sizes, int n_in,
                              void* d_out, int out_size, void* d_ws, size_t ws_size,
                              hipStream_t stream) {
  const float* x      = (const float*)d_in[0];
  const float* noise  = (const float*)d_in[1];
  const float* gate_w = (const float*)d_in[2];
  const float* gate_b = (const float*)d_in[3];
  const float* ew     = (const float*)d_in[4];
  const float* eb     = (const float*)d_in[5];
  const float* pw     = (const float*)d_in[6];
  const float* pb     = (const float*)d_in[7];
  float* out = (float*)d_out;

  char* ws = (char*)d_ws;
  float* scores = (float*)(ws);                               // 25165824 B
  float* y      = (float*)(ws + 25165824);                    // 1048576 B
  float* topw   = (float*)(ws + 26214400);                    // 16384 B
  int*   idx    = (int*)  (ws + 26230784);                    // 16384 B
  int*   counts = (int*)  (ws + 26247168);                    // 6144 B
  int*   offs   = (int*)  (ws + 26253312);                    // 6144 B
  int*   cursor = (int*)  (ws + 26259456);                    // 6144 B
  int*   sorted = (int*)  (ws + 26265600);                    // 16384 B

  hipMemsetAsync(counts, 0, NE * sizeof(int), stream);

  dim3 g1(NT / 128, NE / 64);
  gate_gemm<<<g1, 256, 0, stream>>>(x, gate_w, gate_b, noise, scores);
  softmax_top1<<<NT / 4, 256, 0, stream>>>(scores, topw, idx, counts);
  scan_offsets<<<1, 256, 0, stream>>>(counts, offs, cursor);
  scatter_tokens<<<NT / 256, 256, 0, stream>>>(idx, cursor, sorted);
  expert_gemm<<<NE, 256, 0, stream>>>(x, ew, eb, counts, offs, sorted, y);
  proj_kernel<<<NT / 8, 256, 0, stream>>>(y, pw, pb, topw, out);
}

// Round 2
// 252.054 us; speedup vs baseline: 1.2385x; 1.2385x over previous
//
#include <hip/hip_runtime.h>
#include <hip/hip_bf16.h>

#define NT 4096      // tokens
#define DIM 768
#define NE 1536      // experts
#define ED 64        // expert dim
#define GAP_THR 8e-3f

typedef __attribute__((ext_vector_type(8))) short short8v;
typedef __attribute__((ext_vector_type(4))) float f32x4;

__device__ __forceinline__ unsigned short f2bf(float f) {
  unsigned int u = __float_as_uint(f);
  unsigned int r = (u + 0x7fffu + ((u >> 16) & 1u)) >> 16;   // RNE
  return (unsigned short)r;
}
__device__ __forceinline__ float bf2f(unsigned short h) {
  return __uint_as_float(((unsigned int)h) << 16);
}

__device__ __forceinline__ void gload16(const void* g, void* l) {
  __builtin_amdgcn_global_load_lds((const __attribute__((address_space(1))) void*)g,
                                   (__attribute__((address_space(3))) void*)l, 16, 0, 0);
}

// ---------------- Kernel 0: fp32 -> (bf16 hi, bf16 lo) split ----------------
__global__ __launch_bounds__(256) void split_bf16(
    const float* __restrict__ src, unsigned short* __restrict__ hi,
    unsigned short* __restrict__ lo, int n4) {
  int i = blockIdx.x * 256 + threadIdx.x;
  if (i >= n4) return;
  float4 v = ((const float4*)src)[i];
  unsigned short h0 = f2bf(v.x), h1 = f2bf(v.y), h2 = f2bf(v.z), h3 = f2bf(v.w);
  ushort4 hv = make_ushort4(h0, h1, h2, h3);
  ushort4 lv = make_ushort4(f2bf(v.x - bf2f(h0)), f2bf(v.y - bf2f(h1)),
                            f2bf(v.z - bf2f(h2)), f2bf(v.w - bf2f(h3)));
  ((ushort4*)hi)[i] = hv;
  ((ushort4*)lo)[i] = lv;
}

// ---------------- Kernel 1: gating GEMM via bf16x3-split MFMA ----------------
// scores[n][e] = x[n,:]·gw[e,:] + gb[e] + 0.1*noise[n][e]
// 128x128 tile, 4 waves (2x2), 64x64 per wave = 4x4 frags of 16x16x32, BK=32.
// LDS granule swizzle g' = g ^ ((row>>1)&3) applied via pre-swizzled global src.
__global__ __launch_bounds__(256) void gate_mfma(
    const unsigned short* __restrict__ xhi, const unsigned short* __restrict__ xlo,
    const unsigned short* __restrict__ ghi, const unsigned short* __restrict__ glo,
    const float* __restrict__ gb, const float* __restrict__ noise,
    float* __restrict__ scores) {
  __shared__ __align__(16) unsigned short sA[2 * 128 * 32];  // [0..4095]=hi, [4096..]=lo
  __shared__ __align__(16) unsigned short sB[2 * 128 * 32];
  const int tid = threadIdx.x;
  const int w = tid >> 6, lane = tid & 63;
  const int wr = w >> 1, wc = w & 1;
  const int bm = blockIdx.x, bn = blockIdx.y;
  const int fr = lane & 15;          // frag row/col within 16
  const int fg = lane >> 4;          // k-granule 0..3
  const int gsw = fg ^ ((fr >> 1) & 3);

  f32x4 acc[4][4];
#pragma unroll
  for (int i = 0; i < 4; i++)
#pragma unroll
    for (int j = 0; j < 4; j++) acc[i][j] = (f32x4){0.f, 0.f, 0.f, 0.f};

  const size_t arow = (size_t)bm * 128 * DIM;
  const size_t brow = (size_t)bn * 128 * DIM;
  // staging geometry (per thread, per half h): dest elem = h*2048 + tid*8
  const int sr_lo = tid >> 2;                      // row within half (0..63)
  const int sg = (tid & 3) ^ ((tid >> 3) & 3);     // pre-swizzled source granule

  for (int kt = 0; kt < DIM; kt += 32) {
    __syncthreads();
#pragma unroll
    for (int h = 0; h < 2; h++) {
      const int r = h * 64 + sr_lo;
      const size_t asrc = arow + (size_t)r * DIM + kt + sg * 8;
      const size_t bsrc = brow + (size_t)r * DIM + kt + sg * 8;
      const int dofs = h * 2048 + w * 512;         // per-wave-uniform dest base (elems)
      gload16(xhi + asrc, &sA[dofs]);
      gload16(xlo + asrc, &sA[4096 + dofs]);
      gload16(ghi + bsrc, &sB[dofs]);
      gload16(glo + bsrc, &sB[4096 + dofs]);
    }
    __syncthreads();

    short8v ah[4], al[4], bh[4], bl[4];
#pragma unroll
    for (int mf = 0; mf < 4; mf++) {
      int ro = (wr * 64 + mf * 16 + fr) * 32 + gsw * 8;
      ah[mf] = *(const short8v*)&sA[ro];
      al[mf] = *(const short8v*)&sA[4096 + ro];
    }
#pragma unroll
    for (int nf = 0; nf < 4; nf++) {
      int ro = (wc * 64 + nf * 16 + fr) * 32 + gsw * 8;
      bh[nf] = *(const short8v*)&sB[ro];
      bl[nf] = *(const short8v*)&sB[4096 + ro];
    }
#pragma unroll
    for (int mf = 0; mf < 4; mf++)
#pragma unroll
      for (int nf = 0; nf < 4; nf++) {
        f32x4 c = acc[mf][nf];
        c = __builtin_amdgcn_mfma_f32_16x16x32_bf16(ah[mf], bh[nf], c, 0, 0, 0);
        c = __builtin_amdgcn_mfma_f32_16x16x32_bf16(ah[mf], bl[nf], c, 0, 0, 0);
        c = __builtin_amdgcn_mfma_f32_16x16x32_bf16(al[mf], bh[nf], c, 0, 0, 0);
        acc[mf][nf] = c;
      }
  }

  // epilogue: + gb + 0.1*noise  (C layout: col = lane&15, row = (lane>>4)*4 + reg)
  const int gm0 = bm * 128 + wr * 64;
  const int gn0 = bn * 128 + wc * 64;
#pragma unroll
  for (int nf = 0; nf < 4; nf++) {
    const int gn = gn0 + nf * 16 + fr;
    const float gbv = gb[gn];
#pragma unroll
    for (int mf = 0; mf < 4; mf++) {
      const int gmb = gm0 + mf * 16 + fg * 4;
#pragma unroll
      for (int reg = 0; reg < 4; reg++) {
        const size_t o = (size_t)(gmb + reg) * NE + gn;
        scores[o] = acc[mf][nf][reg] + gbv + 0.1f * noise[o];
      }
    }
  }
}

// ---------------- Kernel 2: softmax top-2 (one wave per token) ----------------
__global__ __launch_bounds__(256) void softmax_top1(
    const float* __restrict__ scores, float* __restrict__ topw,
    int* __restrict__ idx, int* __restrict__ rc_count,
    int* __restrict__ rc_n, int* __restrict__ rc_i2) {
  const int widx = threadIdx.x >> 6;
  const int lane = threadIdx.x & 63;
  const int n = blockIdx.x * 4 + widx;
  const float* s = scores + (size_t)n * NE;

  float v[24];
  float m1 = -1e30f, m2 = -1e30f;
  int i1 = 0, i2 = 0;
#pragma unroll
  for (int j = 0; j < 24; j++) {
    int ii = lane + 64 * j;
    v[j] = s[ii];
    if (v[j] > m1) { m2 = m1; i2 = i1; m1 = v[j]; i1 = ii; }
    else if (v[j] > m2) { m2 = v[j]; i2 = ii; }
  }
#pragma unroll
  for (int off = 32; off; off >>= 1) {
    float om1 = __shfl_xor(m1, off, 64); int oi1 = __shfl_xor(i1, off, 64);
    float om2 = __shfl_xor(m2, off, 64); int oi2 = __shfl_xor(i2, off, 64);
    if (om1 > m1 || (om1 == m1 && oi1 < i1)) {
      if (m1 > om2 || (m1 == om2 && i1 < oi2)) { m2 = m1; i2 = i1; }
      else { m2 = om2; i2 = oi2; }
      m1 = om1; i1 = oi1;
    } else {
      if (om1 > m2 || (om1 == m2 && oi1 < i2)) { m2 = om1; i2 = oi1; }
    }
  }
  float sum = 0.f;
#pragma unroll
  for (int j = 0; j < 24; j++) sum += __expf(v[j] - m1);
#pragma unroll
  for (int off = 32; off; off >>= 1) sum += __shfl_xor(sum, off, 64);

  if (lane == 0) {
    topw[n] = 1.0f / sum;
    idx[n] = i1;
    if (m1 - m2 < GAP_THR) {
      int p = atomicAdd(rc_count, 1);
      rc_n[p] = n; rc_i2[p] = i2;
    }
  }
}

// ---------------- Kernel 2b: fp32 exact recheck of near-tied top-2 ----------------
__global__ __launch_bounds__(256) void recheck(
    const float* __restrict__ x, const float* __restrict__ gw,
    const float* __restrict__ gb, const float* __restrict__ noise,
    const int* __restrict__ rc_n, const int* __restrict__ rc_i2,
    const int* __restrict__ rc_count, int* __restrict__ idx) {
  __shared__ float r1[4], r2[4];
  const int cnt = *rc_count;
  const int tid = threadIdx.x;
  const int w = tid >> 6, lane = tid & 63;
  for (int t = blockIdx.x; t < cnt; t += gridDim.x) {
    const int n = rc_n[t];
    const int e1 = idx[n], e2 = rc_i2[t];
    const float* xr = x + (size_t)n * DIM;
    const float* w1 = gw + (size_t)e1 * DIM;
    const float* w2 = gw + (size_t)e2 * DIM;
    float p1 = 0.f, p2 = 0.f;
    for (int k = tid; k < DIM; k += 256) {
      float xv = xr[k];
      p1 += xv * w1[k];
      p2 += xv * w2[k];
    }
#pragma unroll
    for (int off = 32; off; off >>= 1) {
      p1 += __shfl_xor(p1, off, 64);
      p2 += __shfl_xor(p2, off, 64);
    }
    if (lane == 0) { r1[w] = p1; r2[w] = p2; }
    __syncthreads();
    if (tid == 0) {
      float s1 = r1[0] + r1[1] + r1[2] + r1[3] + gb[e1] + 0.1f * noise[(size_t)n * NE + e1];
      float s2 = r2[0] + r2[1] + r2[2] + r2[3] + gb[e2] + 0.1f * noise[(size_t)n * NE + e2];
      if (s2 > s1 || (s2 == s1 && e2 < e1)) idx[n] = e2;
    }
    __syncthreads();
  }
}

// ---------------- Kernel 2c: expert histogram ----------------
__global__ __launch_bounds__(256) void count_experts(
    const int* __restrict__ idx, int* __restrict__ counts) {
  const int n = blockIdx.x * 256 + threadIdx.x;
  atomicAdd(counts + idx[n], 1);
}

// ---------------- Kernel 3: exclusive scan of counts (1536 = 256*6) ----------------
__global__ __launch_bounds__(256) void scan_offsets(
    const int* __restrict__ counts, int* __restrict__ offs, int* __restrict__ cursor) {
  __shared__ int part[256];
  const int t = threadIdx.x;
  int loc[6];
  int s = 0;
#pragma unroll
  for (int j = 0; j < 6; j++) { loc[j] = counts[t * 6 + j]; s += loc[j]; }
  part[t] = s;
  __syncthreads();
  for (int d = 1; d < 256; d <<= 1) {
    int v2 = (t >= d) ? part[t - d] : 0;
    __syncthreads();
    part[t] += v2;
    __syncthreads();
  }
  int excl = part[t] - s;
#pragma unroll
  for (int j = 0; j < 6; j++) {
    offs[t * 6 + j] = excl;
    cursor[t * 6 + j] = excl;
    excl += loc[j];
  }
}

// ---------------- Kernel 4: scatter token ids grouped by expert ----------------
__global__ __launch_bounds__(256) void scatter_tokens(
    const int* __restrict__ idx, int* __restrict__ cursor, int* __restrict__ sorted) {
  const int n = blockIdx.x * 256 + threadIdx.x;
  int e = idx[n];
  int pos = atomicAdd(cursor + e, 1);
  sorted[pos] = n;
}

// ---------------- Kernel 5: per-expert GEMV batch ----------------
__global__ __launch_bounds__(256) void expert_gemm(
    const float* __restrict__ x, const float* __restrict__ ew,
    const float* __restrict__ eb, const int* __restrict__ counts,
    const int* __restrict__ offs, const int* __restrict__ sorted,
    float* __restrict__ y) {
  const int e = blockIdx.x;
  const int cnt = counts[e];
  if (cnt == 0) return;
  const int base = offs[e];
  __shared__ float4 xs4[8 * 192];
  __shared__ int tok[8];
  const int tid = threadIdx.x;
  const int w = tid >> 6;
  const int lane = tid & 63;
  const float4* W4 = (const float4*)(ew + (size_t)e * ED * DIM);
  const float4* X4 = (const float4*)x;

  for (int c0 = 0; c0 < cnt; c0 += 8) {
    int cc = min(8, cnt - c0);
    __syncthreads();
    if (tid < cc) tok[tid] = sorted[base + c0 + tid];
    __syncthreads();
    int nf = cc * 192;
    for (int f = tid; f < nf; f += 256) {
      int t = f / 192, p = f % 192;
      xs4[t * 192 + p] = X4[(size_t)tok[t] * 192 + p];
    }
    __syncthreads();

    for (int oi = 0; oi < 16; oi++) {
      int o = w * 16 + oi;
      float4 w4a = W4[(size_t)o * 192 + lane];
      float4 w4b = W4[(size_t)o * 192 + lane + 64];
      float4 w4c = W4[(size_t)o * 192 + lane + 128];
      for (int t = 0; t < cc; t++) {
        float4 xa = xs4[t * 192 + lane];
        float4 xb = xs4[t * 192 + lane + 64];
        float4 xc = xs4[t * 192 + lane + 128];
        float p = w4a.x * xa.x + w4a.y * xa.y + w4a.z * xa.z + w4a.w * xa.w;
        p += w4b.x * xb.x + w4b.y * xb.y + w4b.z * xb.z + w4b.w * xb.w;
        p += w4c.x * xc.x + w4c.y * xc.y + w4c.z * xc.z + w4c.w * xc.w;
#pragma unroll
        for (int off = 32; off; off >>= 1) p += __shfl_xor(p, off, 64);
        if (lane == 0) y[(size_t)tok[t] * ED + o] = p + eb[e * ED + o];
      }
    }
  }
}

// ---------------- Kernel 6: projection + scale by top_w ----------------
__global__ __launch_bounds__(256) void proj_kernel(
    const float* __restrict__ y, const float* __restrict__ pw,
    const float* __restrict__ pb, const float* __restrict__ topw,
    float* __restrict__ out) {
  const int b = blockIdx.x;
  const int tid = threadIdx.x;
  __shared__ float4 ys4[8 * 16];
  __shared__ float tw[8];
  if (tid < 128) {
    int t = tid >> 4, q = tid & 15;
    ys4[tid] = ((const float4*)y)[((size_t)b * 8 + t) * 16 + q];
  }
  if (tid < 8) tw[tid] = topw[b * 8 + tid];
  __syncthreads();
  const float4* pw4 = (const float4*)pw;
  for (int c = 0; c < 3; c++) {
    int d = c * 256 + tid;
    float4 pwv[16];
#pragma unroll
    for (int q = 0; q < 16; q++) pwv[q] = pw4[(size_t)d * 16 + q];
    float pbv = pb[d];
    for (int t = 0; t < 8; t++) {
      float s = 0.f;
#pragma unroll
      for (int q = 0; q < 16; q++) {
        float4 yv = ys4[t * 16 + q];
        s += pwv[q].x * yv.x + pwv[q].y * yv.y + pwv[q].z * yv.z + pwv[q].w * yv.w;
      }
      out[((size_t)b * 8 + t) * DIM + d] = (s + pbv) * tw[t];
    }
  }
}

// ---------------- launch ----------------
extern "C" void kernel_launch(void* const* d_in, const int* in_sizes, int n_in,
                              void* d_out, int out_size, void* d_ws, size_t ws_size,
                              hipStream_t stream) {
  const float* x      = (const float*)d_in[0];
  const float* noise  = (const float*)d_in[1];
  const float* gate_w = (const float*)d_in[2];
  const float* gate_b = (const float*)d_in[3];
  const float* ew     = (const float*)d_in[4];
  const float* eb     = (const float*)d_in[5];
  const float* pw     = (const float*)d_in[6];
  const float* pb     = (const float*)d_in[7];
  float* out = (float*)d_out;

  char* ws = (char*)d_ws;
  float*          scores = (float*)(ws);                         // 25165824 B
  unsigned short* xhi    = (unsigned short*)(ws + 25165824);     //  6291456 B
  unsigned short* xlo    = (unsigned short*)(ws + 31457280);     //  6291456 B
  unsigned short* ghi    = (unsigned short*)(ws + 37748736);     //  2359296 B
  unsigned short* glo    = (unsigned short*)(ws + 40108032);     //  2359296 B
  float*          y      = (float*)(ws + 42467328);              //  1048576 B
  float*          topw   = (float*)(ws + 43515904);              //    16384 B
  int*            idx    = (int*)  (ws + 43532288);              //    16384 B
  int*            counts = (int*)  (ws + 43548672);              //     6144 B
  int*            rc_cnt = (int*)  (ws + 43554816);              //        4 B (adj. to counts)
  int*            offs   = (int*)  (ws + 43555072);              //     6144 B
  int*            cursor = (int*)  (ws + 43561216);              //     6144 B
  int*            sorted = (int*)  (ws + 43567360);              //    16384 B
  int*            rc_n   = (int*)  (ws + 43583744);              //    16384 B
  int*            rc_i2  = (int*)  (ws + 43600128);              //    16384 B

  hipMemsetAsync(counts, 0, NE * sizeof(int) + 4, stream);  // counts + rc_cnt

  split_bf16<<<NT * DIM / 4 / 256, 256, 0, stream>>>(x, xhi, xlo, NT * DIM / 4);
  split_bf16<<<NE * DIM / 4 / 256, 256, 0, stream>>>(gate_w, ghi, glo, NE * DIM / 4);
  gate_mfma<<<dim3(NT / 128, NE / 128), 256, 0, stream>>>(xhi, xlo, ghi, glo, gate_b, noise, scores);
  softmax_top1<<<NT / 4, 256, 0, stream>>>(scores, topw, idx, rc_cnt, rc_n, rc_i2);
  recheck<<<32, 256, 0, stream>>>(x, gate_w, gate_b, noise, rc_n, rc_i2, rc_cnt, idx);
  count_experts<<<NT / 256, 256, 0, stream>>>(idx, counts);
  scan_offsets<<<1, 256, 0, stream>>>(counts, offs, cursor);
  scatter_tokens<<<NT / 256, 256, 0, stream>>>(idx, cursor, sorted);
  expert_gemm<<<NE, 256, 0, stream>>>(x, ew, eb, counts, offs, sorted, y);
  proj_kernel<<<NT / 8, 256, 0, stream>>>(y, pw, pb, topw, out);
}